// Round 2
// baseline (6301.022 us; speedup 1.0000x reference)
//
#include <hip/hip_runtime.h>
#include <math.h>

// Problem constants
// V=32000 S=64 T=64 B=64 E=128 EH=256 DH=256
// 3EH=768, 2EH=512, dec in = 640, pred in = 896

__device__ __forceinline__ float sigmoidf_(float x) { return 1.0f / (1.0f + expf(-x)); }

typedef __attribute__((ext_vector_type(8))) short bf16x8;
typedef __attribute__((ext_vector_type(4))) float f32x4;
typedef __attribute__((ext_vector_type(8))) unsigned short ushort8;

__device__ __forceinline__ unsigned short f2bf(float f) {
  unsigned u = __float_as_uint(f);
  unsigned r = (u + 0x7fffu + ((u >> 16) & 1u)) >> 16;
  return (unsigned short)r;
}

__global__ __launch_bounds__(256) void k_zero(float* __restrict__ p, int n4) {
  int i = blockIdx.x * 256 + threadIdx.x;
  if (i < n4) ((float4*)p)[i] = make_float4(0.f, 0.f, 0.f, 0.f);
}

// fp32 -> bf16 (RNE), 8 elements per thread, grid-stride
__global__ __launch_bounds__(256) void k_cvt_bf16(const float* __restrict__ in,
                                                  unsigned short* __restrict__ out, int n8) {
  int i = blockIdx.x * 256 + threadIdx.x;
  int stride = gridDim.x * 256;
  for (; i < n8; i += stride) {
    float4 a = ((const float4*)in)[2 * i];
    float4 b = ((const float4*)in)[2 * i + 1];
    ushort8 v;
    v[0] = f2bf(a.x); v[1] = f2bf(a.y); v[2] = f2bf(a.z); v[3] = f2bf(a.w);
    v[4] = f2bf(b.x); v[5] = f2bf(b.y); v[6] = f2bf(b.z); v[7] = f2bf(b.w);
    ((ushort8*)out)[i] = v;
  }
}

// fp32 column-slice -> bf16: out[r][0:cols] = in[r][col0:col0+cols], cols%8==0
__global__ __launch_bounds__(256) void k_cvt_slice(const float* __restrict__ in,
                                                   unsigned short* __restrict__ out,
                                                   int rows, int ld, int col0, int cols) {
  int g = blockIdx.x * 256 + threadIdx.x;
  int c8 = cols >> 3;
  int n8 = rows * c8;
  if (g < n8) {
    int r = g / c8, c = g % c8;
    const float* p = in + (size_t)r * ld + col0 + c * 8;
    float4 a = ((const float4*)p)[0];
    float4 b = ((const float4*)p)[1];
    ushort8 v;
    v[0] = f2bf(a.x); v[1] = f2bf(a.y); v[2] = f2bf(a.z); v[3] = f2bf(a.w);
    v[4] = f2bf(b.x); v[5] = f2bf(b.y); v[6] = f2bf(b.z); v[7] = f2bf(b.w);
    ((ushort8*)(out + (size_t)r * cols + c * 8))[0] = v;
  }
}

// gather rows of 128 floats: out[r] = tab[idx[r]]
__global__ __launch_bounds__(256) void k_gather(const float* __restrict__ tab,
                                                const int* __restrict__ idx,
                                                float* __restrict__ out, int rows) {
  int g = blockIdx.x * 256 + threadIdx.x;
  int row = g >> 5, c = g & 31;
  if (row < rows) {
    int tok = idx[row];
    ((float4*)(out + (size_t)row * 128))[c] = ((const float4*)(tab + (size_t)tok * 128))[c];
  }
}

// Z[:,768:896] = embd_all (done once, outside the decoder loop)
__global__ __launch_bounds__(256) void k_embZ(const float* __restrict__ emb,
                                              float* __restrict__ Z) {
  int g = blockIdx.x * 256 + threadIdx.x;
  int row = g >> 5, c = g & 31;
  if (row < 4032)
    ((float4*)(Z + (size_t)row * 896 + 768))[c] = ((const float4*)(emb + (size_t)row * 128))[c];
}

// C[m,n] = sum_k A[m*lda+k]*B[n*ldb+k] + bias[n].  M%64==0 (grid.y), N%64==0, K%16==0.
__global__ __launch_bounds__(256) void k_gemm_nt(const float* __restrict__ A, int lda,
                                                 const float* __restrict__ Bm, int ldb,
                                                 const float* __restrict__ bias,
                                                 float* __restrict__ C, int ldc, int K) {
  __shared__ float As[16][68];
  __shared__ float Bs[16][68];
  int tid = threadIdx.x;
  int m0 = blockIdx.y * 64, n0 = blockIdx.x * 64;
  int lm = tid >> 2, lk = (tid & 3) * 4;
  int tm = (tid >> 4) * 4, tn = (tid & 15) * 4;
  float acc[4][4] = {};
  for (int k0 = 0; k0 < K; k0 += 16) {
    float4 av = *(const float4*)(A + (size_t)(m0 + lm) * lda + k0 + lk);
    float4 bv = *(const float4*)(Bm + (size_t)(n0 + lm) * ldb + k0 + lk);
    __syncthreads();
    As[lk + 0][lm] = av.x; As[lk + 1][lm] = av.y; As[lk + 2][lm] = av.z; As[lk + 3][lm] = av.w;
    Bs[lk + 0][lm] = bv.x; Bs[lk + 1][lm] = bv.y; Bs[lk + 2][lm] = bv.z; Bs[lk + 3][lm] = bv.w;
    __syncthreads();
#pragma unroll
    for (int k = 0; k < 16; k++) {
      float4 a4 = *(const float4*)&As[k][tm];
      float4 b4 = *(const float4*)&Bs[k][tn];
      float ar[4] = {a4.x, a4.y, a4.z, a4.w};
      float br[4] = {b4.x, b4.y, b4.z, b4.w};
#pragma unroll
      for (int i = 0; i < 4; i++)
#pragma unroll
        for (int j = 0; j < 4; j++) acc[i][j] += ar[i] * br[j];
    }
  }
  float4 bb = *(const float4*)(bias + n0 + tn);
  float br[4] = {bb.x, bb.y, bb.z, bb.w};
#pragma unroll
  for (int i = 0; i < 4; i++) {
    float* crow = C + (size_t)(m0 + tm + i) * ldc + n0 + tn;
    *(float4*)crow = make_float4(acc[i][0] + br[0], acc[i][1] + br[1],
                                 acc[i][2] + br[2], acc[i][3] + br[3]);
  }
}

// Persistent encoder scan: one block per (dir, b). 128 blocks, no cross-block deps.
__global__ __launch_bounds__(256) void k_enc_scan(
    const float* __restrict__ gi_f, const float* __restrict__ gi_b,
    const float* __restrict__ Whh_f, const float* __restrict__ Whh_b,
    const float* __restrict__ bhh_f, const float* __restrict__ bhh_b,
    float* __restrict__ hf_out, float* __restrict__ hb_out,
    float* __restrict__ enc_bse) {
  int blk = blockIdx.x;
  int dir = blk >> 6, b = blk & 63;
  int j = threadIdx.x;
  const float* gi  = dir ? gi_b  : gi_f;
  const float* Whh = dir ? Whh_b : Whh_f;
  const float* bhh = dir ? bhh_b : bhh_f;
  __shared__ float h_s[256];
  h_s[j] = 0.f;
  float bh_r = bhh[j], bh_z = bhh[256 + j], bh_n = bhh[512 + j];
  const float4* wr = (const float4*)(Whh + (size_t)j * 256);
  const float4* wz = (const float4*)(Whh + (size_t)(256 + j) * 256);
  const float4* wn = (const float4*)(Whh + (size_t)(512 + j) * 256);
  const float4* hv = (const float4*)h_s;
  __syncthreads();
  float h2 = 0.f;
  for (int t = 0; t < 64; t++) {
    int s = dir ? (63 - t) : t;
    float hr = bh_r, hz = bh_z, hn = bh_n;
#pragma unroll 8
    for (int k = 0; k < 64; k++) {
      float4 h4 = hv[k];
      float4 r4 = wr[k], z4 = wz[k], n4 = wn[k];
      hr += h4.x * r4.x + h4.y * r4.y + h4.z * r4.z + h4.w * r4.w;
      hz += h4.x * z4.x + h4.y * z4.y + h4.z * z4.z + h4.w * z4.w;
      hn += h4.x * n4.x + h4.y * n4.y + h4.z * n4.z + h4.w * n4.w;
    }
    size_t gib = (size_t)(s * 64 + b) * 768;
    float r = sigmoidf_(gi[gib + j] + hr);
    float z = sigmoidf_(gi[gib + 256 + j] + hz);
    float n = tanhf(gi[gib + 512 + j] + r * hn);
    h2 = (1.f - z) * n + z * h_s[j];
    __syncthreads();           // all reads of h_s (t) done
    h_s[j] = h2;
    enc_bse[((size_t)b * 64 + s) * 512 + dir * 256 + j] = h2;
    __syncthreads();           // h_s (t+1) visible to all
  }
  (dir ? hb_out : hf_out)[b * 256 + j] = h2;
}

// hidden = tanh([h_f,h_b] @ enc_fc_W.T + b)
__global__ __launch_bounds__(256) void k_hidden(const float* __restrict__ hf,
                                                const float* __restrict__ hb,
                                                const float* __restrict__ W,
                                                const float* __restrict__ bias,
                                                float* __restrict__ hdec) {
  int b = blockIdx.x, j = threadIdx.x;
  __shared__ float cat[512];
  cat[j] = hf[b * 256 + j];
  cat[256 + j] = hb[b * 256 + j];
  __syncthreads();
  const float4* wrow = (const float4*)(W + (size_t)j * 512);
  const float4* cv = (const float4*)cat;
  float acc = 0.f;
#pragma unroll 8
  for (int k = 0; k < 128; k++) {
    float4 w4 = wrow[k], c4 = cv[k];
    acc += w4.x * c4.x + w4.y * c4.y + w4.z * c4.z + w4.w * c4.w;
  }
  hdec[b * 256 + j] = tanhf(acc + bias[j]);
}

// Persistent decoder scan: one block per b, loops t=0..62. No cross-block deps.
// Uses PRE[b,s,:] = enc_bse[b,s,:] @ dWih[:,128:640].T so the per-step gi is a
// 64-long weighted sum instead of a 512-wide matvec.
__global__ __launch_bounds__(256) void k_dec_scan(
    const float* __restrict__ h0, const float* __restrict__ attn_W,
    const float* __restrict__ attn_v, const float* __restrict__ enc_proj,
    const float* __restrict__ enc_bse, const float* __restrict__ PRE,
    const float* __restrict__ gi_emb, const float* __restrict__ Whh,
    const float* __restrict__ bhh, float* __restrict__ Z) {
  int b = blockIdx.x, tid = threadIdx.x;
  __shared__ float h_s[256], hW_s[256], v_s[256], sc[64];
  h_s[tid] = h0[b * 256 + tid];
  v_s[tid] = attn_v[tid];
  float bh_r = bhh[tid], bh_z = bhh[256 + tid], bh_n = bhh[512 + tid];
  const float4* wrow = (const float4*)(attn_W + (size_t)tid * 768);  // W_h rows
  const float4* ur = (const float4*)(Whh + (size_t)tid * 256);
  const float4* uz = (const float4*)(Whh + (size_t)(256 + tid) * 256);
  const float4* un = (const float4*)(Whh + (size_t)(512 + tid) * 256);
  const float4* hv = (const float4*)h_s;
  const float* eb = enc_bse + (size_t)b * 64 * 512;
  const float* pr = PRE + (size_t)b * 64 * 768;
  __syncthreads();
  for (int t = 0; t < 63; t++) {
    // phase 1: hW = W_h @ h
    {
      float acc = 0.f;
#pragma unroll 8
      for (int k = 0; k < 64; k++) {
        float4 w4 = wrow[k], h4 = hv[k];
        acc += w4.x * h4.x + w4.y * h4.y + w4.z * h4.z + w4.w * h4.w;
      }
      hW_s[tid] = acc;
    }
    __syncthreads();
    // phase 2: scores
    {
      int w = tid >> 6, l = tid & 63;
      for (int s = w; s < 64; s += 4) {
        const float* ep = enc_proj + ((size_t)b * 64 + s) * 256;
        float p = 0.f;
#pragma unroll
        for (int i = 0; i < 4; i++) {
          int hh = l + i * 64;
          p += v_s[hh] * tanhf(ep[hh] + hW_s[hh]);
        }
#pragma unroll
        for (int o = 32; o > 0; o >>= 1) p += __shfl_xor(p, o, 64);
        if (l == 0) sc[s] = p;
      }
    }
    __syncthreads();
    if (tid < 64) {
      float x = sc[tid], m = x;
#pragma unroll
      for (int o = 32; o > 0; o >>= 1) m = fmaxf(m, __shfl_xor(m, o, 64));
      float e = expf(x - m), ssum = e;
#pragma unroll
      for (int o = 32; o > 0; o >>= 1) ssum += __shfl_xor(ssum, o, 64);
      sc[tid] = e / ssum;
    }
    __syncthreads();
    // phase 3: weighted + attention part of gi
    size_t zr = (size_t)(t * 64 + b) * 896;
    float w0 = 0.f, w1 = 0.f, gwr = 0.f, gwz = 0.f, gwn = 0.f;
#pragma unroll 4
    for (int s = 0; s < 64; s++) {
      float a = sc[s];
      w0 += a * eb[s * 512 + tid];
      w1 += a * eb[s * 512 + 256 + tid];
      gwr += a * pr[s * 768 + tid];
      gwz += a * pr[s * 768 + 256 + tid];
      gwn += a * pr[s * 768 + 512 + tid];
    }
    Z[zr + 256 + tid] = w0;
    Z[zr + 512 + tid] = w1;
    // phase 4: gh + gates + h update
    float hr = bh_r, hz = bh_z, hn = bh_n;
#pragma unroll 8
    for (int k = 0; k < 64; k++) {
      float4 h4 = hv[k];
      float4 r4 = ur[k], z4 = uz[k], n4 = un[k];
      hr += h4.x * r4.x + h4.y * r4.y + h4.z * r4.z + h4.w * r4.w;
      hz += h4.x * z4.x + h4.y * z4.y + h4.z * z4.z + h4.w * z4.w;
      hn += h4.x * n4.x + h4.y * n4.y + h4.z * n4.z + h4.w * n4.w;
    }
    size_t gib = (size_t)(t * 64 + b) * 768;
    float r = sigmoidf_(gi_emb[gib + tid] + gwr + hr);
    float z = sigmoidf_(gi_emb[gib + 256 + tid] + gwz + hz);
    float n = tanhf(gi_emb[gib + 512 + tid] + gwn + r * hn);
    float h2 = (1.f - z) * n + z * h_s[tid];
    __syncthreads();           // all reads of h_s (t) done
    h_s[tid] = h2;
    Z[zr + tid] = h2;
    __syncthreads();           // h_s (t+1) visible
  }
}

// Generic bf16 MFMA GEMM (m97 structure): C[m,n] = A[m,:K].B[n,:K] (+bias).
// M = grid.y*128, N = grid.x*128, K%64==0. C is fp32 with row stride ldc.
__global__ __launch_bounds__(256) void k_gemm_mfma(const unsigned short* __restrict__ A16,
                                                   const unsigned short* __restrict__ B16,
                                                   const float* __restrict__ bias,
                                                   float* __restrict__ C, int K, int ldc) {
  __shared__ unsigned short As[128 * 64];
  __shared__ unsigned short Bs[128 * 64];
  int tid = threadIdx.x;
  int l = tid & 63, w = tid >> 6;
  int m0 = blockIdx.y * 128, n0 = blockIdx.x * 128;
  int wr = w >> 1, wc = w & 1;
  f32x4 acc[4][4] = {};
  int lrow = l >> 3, lk = (l & 7) * 8;
  for (int k0 = 0; k0 < K; k0 += 64) {
    __syncthreads();
#pragma unroll
    for (int i = 0; i < 4; i++) {
      int c = i * 4 + w;
      const unsigned short* ga = A16 + (size_t)(m0 + c * 8 + lrow) * K + k0 + lk;
      const unsigned short* gb = B16 + (size_t)(n0 + c * 8 + lrow) * K + k0 + lk;
      __builtin_amdgcn_global_load_lds((const __attribute__((address_space(1))) void*)ga,
                                       (__attribute__((address_space(3))) void*)&As[c * 512],
                                       16, 0, 0);
      __builtin_amdgcn_global_load_lds((const __attribute__((address_space(1))) void*)gb,
                                       (__attribute__((address_space(3))) void*)&Bs[c * 512],
                                       16, 0, 0);
    }
    __syncthreads();
#pragma unroll
    for (int ks = 0; ks < 2; ks++) {
      bf16x8 aF[4], bF[4];
#pragma unroll
      for (int i = 0; i < 4; i++)
        aF[i] = *(const bf16x8*)&As[(wr * 64 + i * 16 + (l & 15)) * 64 + ks * 32 + (l >> 4) * 8];
#pragma unroll
      for (int j = 0; j < 4; j++)
        bF[j] = *(const bf16x8*)&Bs[(wc * 64 + j * 16 + (l & 15)) * 64 + ks * 32 + (l >> 4) * 8];
#pragma unroll
      for (int i = 0; i < 4; i++)
#pragma unroll
        for (int j = 0; j < 4; j++)
          acc[i][j] = __builtin_amdgcn_mfma_f32_16x16x32_bf16(aF[i], bF[j], acc[i][j], 0, 0, 0);
    }
  }
  int cl = l & 15, rg = l >> 4;
#pragma unroll
  for (int j = 0; j < 4; j++) {
    int n = n0 + wc * 64 + j * 16 + cl;
    float bb = bias ? bias[n] : 0.f;
#pragma unroll
    for (int i = 0; i < 4; i++) {
      int mb = m0 + wr * 64 + i * 16 + rg * 4;
#pragma unroll
      for (int r = 0; r < 4; r++)
        C[(size_t)(mb + r) * ldc + n] = acc[i][j][r] + bb;
    }
  }
}

// Final vocab GEMM via bf16 MFMA.
__global__ __launch_bounds__(256) void k_fc_mfma(const unsigned short* __restrict__ Zb16,
                                                 const unsigned short* __restrict__ Wb16,
                                                 const float* __restrict__ bias,
                                                 float* __restrict__ out) {
  __shared__ unsigned short As[128 * 64];
  __shared__ unsigned short Bs[128 * 64];
  int tid = threadIdx.x;
  int l = tid & 63, w = tid >> 6;
  int m0 = blockIdx.y * 128, n0 = blockIdx.x * 128;
  int wr = w >> 1, wc = w & 1;
  f32x4 acc[4][4] = {};
  int lrow = l >> 3, lk = (l & 7) * 8;
  for (int k0 = 0; k0 < 896; k0 += 64) {
    __syncthreads();
#pragma unroll
    for (int i = 0; i < 4; i++) {
      int c = i * 4 + w;
      const unsigned short* ga = Zb16 + (size_t)(m0 + c * 8 + lrow) * 896 + k0 + lk;
      const unsigned short* gb = Wb16 + (size_t)(n0 + c * 8 + lrow) * 896 + k0 + lk;
      __builtin_amdgcn_global_load_lds((const __attribute__((address_space(1))) void*)ga,
                                       (__attribute__((address_space(3))) void*)&As[c * 512],
                                       16, 0, 0);
      __builtin_amdgcn_global_load_lds((const __attribute__((address_space(1))) void*)gb,
                                       (__attribute__((address_space(3))) void*)&Bs[c * 512],
                                       16, 0, 0);
    }
    __syncthreads();
#pragma unroll
    for (int ks = 0; ks < 2; ks++) {
      bf16x8 aF[4], bF[4];
#pragma unroll
      for (int i = 0; i < 4; i++)
        aF[i] = *(const bf16x8*)&As[(wr * 64 + i * 16 + (l & 15)) * 64 + ks * 32 + (l >> 4) * 8];
#pragma unroll
      for (int j = 0; j < 4; j++)
        bF[j] = *(const bf16x8*)&Bs[(wc * 64 + j * 16 + (l & 15)) * 64 + ks * 32 + (l >> 4) * 8];
#pragma unroll
      for (int i = 0; i < 4; i++)
#pragma unroll
        for (int j = 0; j < 4; j++)
          acc[i][j] = __builtin_amdgcn_mfma_f32_16x16x32_bf16(aF[i], bF[j], acc[i][j], 0, 0, 0);
    }
  }
  int cl = l & 15, rg = l >> 4;
#pragma unroll
  for (int j = 0; j < 4; j++) {
    int n = n0 + wc * 64 + j * 16 + cl;
    float bb = bias[n];
#pragma unroll
    for (int i = 0; i < 4; i++) {
      int mb = m0 + wr * 64 + i * 16 + rg * 4;
#pragma unroll
      for (int r = 0; r < 4; r++) {
        int m = mb + r;
        if (m < 4032) out[(size_t)(m + 64) * 32000 + n] = acc[i][j][r] + bb;
      }
    }
  }
}

extern "C" void kernel_launch(void* const* d_in, const int* in_sizes, int n_in,
                              void* d_out, int out_size, void* d_ws, size_t ws_size,
                              hipStream_t stream) {
  const int* src = (const int*)d_in[0];
  const int* trg = (const int*)d_in[1];
  const float* enc_emb = (const float*)d_in[2];
  const float* eWih_f  = (const float*)d_in[3];
  const float* eWhh_f  = (const float*)d_in[4];
  const float* ebih_f  = (const float*)d_in[5];
  const float* ebhh_f  = (const float*)d_in[6];
  const float* eWih_b  = (const float*)d_in[7];
  const float* eWhh_b  = (const float*)d_in[8];
  const float* ebih_b  = (const float*)d_in[9];
  const float* ebhh_b  = (const float*)d_in[10];
  const float* efc_W   = (const float*)d_in[11];
  const float* efc_b   = (const float*)d_in[12];
  const float* attn_W  = (const float*)d_in[13];
  const float* attn_b  = (const float*)d_in[14];
  const float* attn_v  = (const float*)d_in[15];
  const float* dec_emb = (const float*)d_in[16];
  const float* dWih    = (const float*)d_in[17];
  const float* dWhh    = (const float*)d_in[18];
  const float* dbih    = (const float*)d_in[19];
  const float* dbhh    = (const float*)d_in[20];
  const float* fc_W    = (const float*)d_in[21];
  const float* fc_b    = (const float*)d_in[22];
  float* out = (float*)d_out;
  float* ws = (float*)d_ws;

  size_t o = 0;
  float* emb_src  = ws + o; o += (size_t)4096 * 128;
  float* embd_all = ws + o; o += (size_t)4032 * 128;
  float* gi_f     = ws + o; o += (size_t)4096 * 768;
  float* gi_b     = ws + o; o += (size_t)4096 * 768;
  float* gi_emb   = ws + o; o += (size_t)4032 * 768;
  float* enc_bse  = ws + o; o += (size_t)4096 * 512;
  float* enc_proj = ws + o; o += (size_t)4096 * 256;
  float* PRE      = ws + o; o += (size_t)4096 * 768;
  float* h_f0 = ws + o; o += 16384;
  float* h_b0 = ws + o; o += 16384;
  float* h_d0 = ws + o; o += 16384;
  float* Zb   = ws + o; o += (size_t)4096 * 896;
  unsigned short* Zb16    = (unsigned short*)(ws + o); o += (size_t)4096 * 896 / 2;
  unsigned short* Wb16    = (unsigned short*)(ws + o); o += (size_t)32000 * 896 / 2;
  unsigned short* eb16    = (unsigned short*)(ws + o); o += (size_t)4096 * 512 / 2;
  unsigned short* Wpre16  = (unsigned short*)(ws + o); o += (size_t)768 * 512 / 2;
  unsigned short* Wproj16 = (unsigned short*)(ws + o); o += (size_t)256 * 512 / 2;

  // init: zero out row t=0, zero Z pad rows (4032..4095)
  k_zero<<<2000, 256, 0, stream>>>(out, 512000);
  k_zero<<<56, 256, 0, stream>>>(Zb + (size_t)4032 * 896, 14336);
  k_gather<<<512, 256, 0, stream>>>(enc_emb, src, emb_src, 4096);
  k_gather<<<504, 256, 0, stream>>>(dec_emb, trg, embd_all, 4032);
  k_embZ<<<504, 256, 0, stream>>>(embd_all, Zb);

  // weight conversions (independent; do up front)
  k_cvt_bf16<<<2048, 256, 0, stream>>>(fc_W, Wb16, 3584000);            // 32000*896/8
  k_cvt_slice<<<192, 256, 0, stream>>>(dWih, Wpre16, 768, 640, 128, 512);
  k_cvt_slice<<<64, 256, 0, stream>>>(attn_W, Wproj16, 256, 768, 256, 512);

  // input-side GEMMs (batched over all time steps)
  k_gemm_nt<<<dim3(12, 64), 256, 0, stream>>>(emb_src, 128, eWih_f, 128, ebih_f, gi_f, 768, 128);
  k_gemm_nt<<<dim3(12, 64), 256, 0, stream>>>(emb_src, 128, eWih_b, 128, ebih_b, gi_b, 768, 128);
  k_gemm_nt<<<dim3(12, 63), 256, 0, stream>>>(embd_all, 128, dWih, 640, dbih, gi_emb, 768, 128);

  // persistent bidirectional encoder scan (one launch, 64 steps inside)
  k_enc_scan<<<128, 256, 0, stream>>>(gi_f, gi_b, eWhh_f, eWhh_b, ebhh_f, ebhh_b,
                                      h_f0, h_b0, enc_bse);
  k_hidden<<<64, 256, 0, stream>>>(h_f0, h_b0, efc_W, efc_b, h_d0);

  // enc_proj and PRE via MFMA: both = f(enc_bse) with K=512
  k_cvt_bf16<<<1024, 256, 0, stream>>>(enc_bse, eb16, 262144);          // 4096*512/8
  k_gemm_mfma<<<dim3(6, 32), 256, 0, stream>>>(eb16, Wpre16, nullptr, PRE, 512, 768);
  k_gemm_mfma<<<dim3(2, 32), 256, 0, stream>>>(eb16, Wproj16, attn_b, enc_proj, 512, 256);

  // persistent decoder scan (one launch, 63 steps inside)
  k_dec_scan<<<64, 256, 0, stream>>>(h_d0, attn_W, attn_v, enc_proj, enc_bse, PRE,
                                     gi_emb, dWhh, dbhh, Zb);

  // batched vocab projection on the matrix cores
  k_cvt_bf16<<<1024, 256, 0, stream>>>(Zb, Zb16, 458752);               // 4096*896/8
  k_fc_mfma<<<dim3(250, 32), 256, 0, stream>>>(Zb16, Wb16, fc_b, out);
}